// Round 2
// baseline (2866.445 us; speedup 1.0000x reference)
//
#include <hip/hip_runtime.h>

#define BB   32
#define TT   2048
#define HH   256
#define G3   768      // 3*H
#define NVOC 18       // vocab rows (V+2)
#define NOUT 17       // head outputs (V+1)
#define LOGITS_ELEMS ((size_t)BB * TT * NOUT)

typedef _Float16 h2 __attribute__((ext_vector_type(2)));

__device__ __forceinline__ float bf1(unsigned short u){
  union{unsigned int i; float f;} v; v.i = ((unsigned int)u) << 16; return v.f;
}
__device__ __forceinline__ unsigned short f2bf(float f){
  union{float f; unsigned int i;} v; v.f = f;
  unsigned int lsb = (v.i >> 16) & 1u;
  v.i += 0x7fffu + lsb;               // round-to-nearest-even
  return (unsigned short)(v.i >> 16);
}
__device__ __forceinline__ float bflo(unsigned int u){
  union{unsigned int i; float f;} v; v.i = u << 16; return v.f;
}
__device__ __forceinline__ float bfhi(unsigned int u){
  union{unsigned int i; float f;} v; v.i = u & 0xffff0000u; return v.f;
}

// dtype-generic scalar load
__device__ __forceinline__ float ld1(const float* p, size_t i){ return p[i]; }
__device__ __forceinline__ float ld1(const unsigned short* p, size_t i){ return bf1(p[i]); }

// Device-side dtype detection: W_ih ~ uniform(-1/16,1/16). If the buffer is
// really f32, the low-half words of the floats decode as bf16 with random
// exponents -> some |v| > 0.25 (P[miss] ~ 0.49^32 ~ 1e-10).
__device__ __forceinline__ bool detect_f32(const void* W_ih_raw){
  const unsigned short* u = (const unsigned short*)W_ih_raw;
  bool big = false;
  #pragma unroll
  for (int i = 0; i < 64; i++){
    float v = bf1(u[i]);
    big |= !(v >= -0.25f && v <= 0.25f);   // catches NaN patterns too
  }
  return big;
}

#if __has_builtin(__builtin_amdgcn_fdot2)
#define FDOT2(a,b,c) __builtin_amdgcn_fdot2((a),(b),(c),false)
#else
#define FDOT2(a,b,c) ((c) + (float)(a).x*(float)(b).x + (float)(a).y*(float)(b).y)
#endif

// ---------------------------------------------------------------------------
// Kernel 1: proj[v][j] = b_ih[j] + sum_k embed[v][k] * W_ih[k][j]  (f32)
// ---------------------------------------------------------------------------
template<typename T>
__device__ __forceinline__ void proj_body(const T* embed, const T* W_ih,
                                          const T* b_ih, float* proj){
  int gid = blockIdx.x * 256 + threadIdx.x;
  if (gid >= NVOC * G3) return;
  int v = gid / G3;
  int j = gid - v * G3;
  float acc = ld1(b_ih, j);
  #pragma unroll 8
  for (int k = 0; k < HH; k++)
    acc += ld1(embed, (size_t)v * HH + k) * ld1(W_ih, (size_t)k * G3 + j);
  proj[gid] = acc;
}

__global__ __launch_bounds__(256) void k_proj(
    const void* __restrict__ embed, const void* __restrict__ W_ih,
    const void* __restrict__ b_ih, float* __restrict__ proj)
{
  if (detect_f32(W_ih))
    proj_body<float>((const float*)embed, (const float*)W_ih,
                     (const float*)b_ih, proj);
  else
    proj_body<unsigned short>((const unsigned short*)embed,
                              (const unsigned short*)W_ih,
                              (const unsigned short*)b_ih, proj);
}

// ---------------------------------------------------------------------------
// Kernel 2: GRU scan. One block per batch element, 768 threads.
// ---------------------------------------------------------------------------
template<typename T>
__device__ __forceinline__ void cache_cols(const T* W_hh, const T* b_hh,
                                           int j, h2* w, float& bhh){
  #pragma unroll
  for (int k = 0; k < 128; k++){
    float a0 = ld1(W_hh, (size_t)(2*k)   * G3 + j);
    float a1 = ld1(W_hh, (size_t)(2*k+1) * G3 + j);
    h2 t; t.x = (_Float16)a0; t.y = (_Float16)a1;
    w[k] = t;
  }
  bhh = ld1(b_hh, j);
}

__global__ __launch_bounds__(768, 1) void k_scan(
    const int*  __restrict__ tokens,
    const void* __restrict__ W_hh,
    const void* __restrict__ b_hh,
    const void* __restrict__ W_ih,     // dtype detection only
    const float* __restrict__ proj,
    unsigned short* __restrict__ outs, // [B,T,H] internal bf16 scratch
    void* __restrict__ d_out_base)     // betas written at +LOGITS_ELEMS
{
  __shared__ float s_proj[NVOC * G3];          // 55296 B
  __shared__ __align__(16) h2 s_h[HH / 2];     // 512 B f16 hidden state
  __shared__ float s_z[HH];
  __shared__ float s_n[HH];

  const bool f32m = detect_f32(W_ih);
  const int b = blockIdx.x;
  const int j = threadIdx.x;

  for (int i = j; i < NVOC * G3; i += 768) s_proj[i] = proj[i];

  h2 w[128]; float bhh;
  if (f32m) cache_cols<float>((const float*)W_hh, (const float*)b_hh, j, w, bhh);
  else      cache_cols<unsigned short>((const unsigned short*)W_hh,
                                       (const unsigned short*)b_hh, j, w, bhh);

  if (j < HH/2) { h2 z; z.x = (_Float16)0.f; z.y = (_Float16)0.f; s_h[j] = z; }
  float h_old = 0.f;   // thread j<256 owns h[j]

  const int* tptr = tokens + (size_t)b * TT;
  int tok = tptr[0];
  const size_t base = (size_t)b * TT * HH + j;
  unsigned short* orow   = outs + base;
  unsigned short* brow_b = (unsigned short*)d_out_base + LOGITS_ELEMS + base;
  float*          brow_f = (float*)d_out_base          + LOGITS_ELEMS + base;

  __syncthreads();

  for (int t = 0; t < TT; t++) {
    int tok_next = (t + 1 < TT) ? tptr[t + 1] : 0;
    const float* pj = s_proj + tok * G3;
    float gi = pj[j];

    // gh[j] = dot(h, W_hh[:,j]) : 32 broadcast b128 LDS reads + 128 dot2
    float a0 = 0.f, a1 = 0.f, a2 = 0.f, a3 = 0.f;
    const int4* hp = (const int4*)s_h;
    #pragma unroll
    for (int kk = 0; kk < 32; kk++) {
      int4 hv = hp[kk];
      a0 = FDOT2(w[4*kk+0], __builtin_bit_cast(h2, hv.x), a0);
      a1 = FDOT2(w[4*kk+1], __builtin_bit_cast(h2, hv.y), a1);
      a2 = FDOT2(w[4*kk+2], __builtin_bit_cast(h2, hv.z), a2);
      a3 = FDOT2(w[4*kk+3], __builtin_bit_cast(h2, hv.w), a3);
    }
    float gh = (a0 + a1) + (a2 + a3) + bhh;

    // wave-uniform gate split: j<256 -> r, 256..511 -> z, 512..767 -> n
    float r = 0.f;
    if (j >= 2*HH) {
      s_n[j - 2*HH] = gh;
    } else if (j >= HH) {
      s_z[j - HH] = 1.f / (1.f + __expf(-(gi + gh)));
    } else {
      r = 1.f / (1.f + __expf(-(gi + gh)));
    }
    __syncthreads();

    if (j < HH) {
      float z = s_z[j];
      float x = pj[2*HH + j] + r * s_n[j];              // i_n + r*h_n
      x = fminf(fmaxf(x, -15.f), 15.f);
      float e = __expf(2.f * x);
      float n = (e - 1.f) / (e + 1.f);                  // tanh
      float hn = (1.f - z) * n + z * h_old;
      h_old = hn;
      ((_Float16*)s_h)[j] = (_Float16)hn;               // publish h
      orow[(size_t)t * HH] = f2bf(hn);
      if (f32m) brow_f[(size_t)t * HH] = z;
      else      brow_b[(size_t)t * HH] = f2bf(z);
    }
    __syncthreads();
    tok = tok_next;
  }
}

// ---------------------------------------------------------------------------
// Kernel 3: logits = outs @ W_head + b_head
// ---------------------------------------------------------------------------
template<typename T>
__device__ __forceinline__ void stage_head(const T* W_head, const T* b_head,
                                           float* s_w, float* s_b, int tid){
  for (int i = tid; i < NOUT * HH; i += 256) {
    int o = i / HH, k = i - o * HH;
    s_w[i] = ld1(W_head, (size_t)k * NOUT + o);
  }
  if (tid < NOUT) s_b[tid] = ld1(b_head, (size_t)tid);
}

__global__ __launch_bounds__(256) void k_head(
    const unsigned short* __restrict__ outs,
    const void* __restrict__ W_head,
    const void* __restrict__ b_head,
    const void* __restrict__ W_ih,     // dtype detection only
    void* __restrict__ logits_out)
{
  __shared__ float s_w[NOUT * HH];
  __shared__ float s_b[NOUT];
  const bool f32m = detect_f32(W_ih);
  const int tid = threadIdx.x;

  if (f32m) stage_head<float>((const float*)W_head, (const float*)b_head,
                              s_w, s_b, tid);
  else      stage_head<unsigned short>((const unsigned short*)W_head,
                                       (const unsigned short*)b_head,
                                       s_w, s_b, tid);
  __syncthreads();

  size_t gid = (size_t)blockIdx.x * 256 + tid;
  if (gid >= LOGITS_ELEMS) return;
  int o = (int)(gid % NOUT);
  size_t row = gid / NOUT;

  const uint4* xp = (const uint4*)(outs + row * HH);   // rows 512B-aligned
  const float* wv = s_w + o * HH;
  float a0 = 0.f, a1 = 0.f, a2 = 0.f, a3 = 0.f;
  #pragma unroll 8
  for (int kk = 0; kk < 32; kk++) {
    uint4 u = xp[kk];
    int kb = kk * 8;
    a0 += bflo(u.x) * wv[kb+0] + bfhi(u.x) * wv[kb+1];
    a1 += bflo(u.y) * wv[kb+2] + bfhi(u.y) * wv[kb+3];
    a2 += bflo(u.z) * wv[kb+4] + bfhi(u.z) * wv[kb+5];
    a3 += bflo(u.w) * wv[kb+6] + bfhi(u.w) * wv[kb+7];
  }
  float val = ((a0 + a1) + (a2 + a3)) + s_b[o];
  if (f32m) ((float*)logits_out)[gid] = val;
  else      ((unsigned short*)logits_out)[gid] = f2bf(val);
}

// ---------------------------------------------------------------------------
extern "C" void kernel_launch(void* const* d_in, const int* in_sizes, int n_in,
                              void* d_out, int out_size, void* d_ws, size_t ws_size,
                              hipStream_t stream)
{
  // setup_inputs order: tokens, embed, W_ih, W_hh, b_ih, b_hh, W_head, b_head
  const int* tokens = (const int*)d_in[0];
  const void* embed  = d_in[1];
  const void* W_ih   = d_in[2];
  const void* W_hh   = d_in[3];
  const void* b_ih   = d_in[4];
  const void* b_hh   = d_in[5];
  const void* W_head = d_in[6];
  const void* b_head = d_in[7];

  float*          proj = (float*)d_ws;                               // 13824 f32
  unsigned short* outs = (unsigned short*)((char*)d_ws + (size_t)NVOC * G3 * 4);

  k_proj<<<(NVOC * G3 + 255) / 256, 256, 0, stream>>>(embed, W_ih, b_ih, proj);
  k_scan<<<BB, 768, 0, stream>>>(tokens, W_hh, b_hh, W_ih, proj, outs, d_out);
  k_head<<<(int)((LOGITS_ELEMS + 255) / 256), 256, 0, stream>>>(
      outs, W_head, b_head, W_ih, d_out);
}

// Round 3
// 2718.318 us; speedup vs baseline: 1.0545x; 1.0545x over previous
//
#include <hip/hip_runtime.h>

#define BB   32
#define TT   2048
#define HH   256
#define G3   768      // 3*H
#define NVOC 18       // vocab rows (V+2)
#define NOUT 17       // head outputs (V+1)
#define LOGITS_ELEMS ((size_t)BB * TT * NOUT)

typedef _Float16 h2 __attribute__((ext_vector_type(2)));

__device__ __forceinline__ float bf1(unsigned short u){
  union{unsigned int i; float f;} v; v.i = ((unsigned int)u) << 16; return v.f;
}
__device__ __forceinline__ unsigned short f2bf(float f){
  union{float f; unsigned int i;} v; v.f = f;
  unsigned int lsb = (v.i >> 16) & 1u;
  v.i += 0x7fffu + lsb;               // round-to-nearest-even
  return (unsigned short)(v.i >> 16);
}
__device__ __forceinline__ float bflo(unsigned int u){
  union{unsigned int i; float f;} v; v.i = u << 16; return v.f;
}
__device__ __forceinline__ float bfhi(unsigned int u){
  union{unsigned int i; float f;} v; v.i = u & 0xffff0000u; return v.f;
}

__device__ __forceinline__ float ld1(const float* p, size_t i){ return p[i]; }
__device__ __forceinline__ float ld1(const unsigned short* p, size_t i){ return bf1(p[i]); }

// Device-side dtype detection: W_ih ~ uniform(-1/16,1/16). If the buffer is
// f32, low-half words decode as bf16 with random exponents -> some |v|>0.25.
__device__ __forceinline__ bool detect_f32(const void* W_ih_raw){
  const unsigned short* u = (const unsigned short*)W_ih_raw;
  bool big = false;
  #pragma unroll
  for (int i = 0; i < 64; i++){
    float v = bf1(u[i]);
    big |= !(v >= -0.25f && v <= 0.25f);
  }
  return big;
}

#if __has_builtin(__builtin_amdgcn_fdot2)
#define FDOT2(a,b,c) __builtin_amdgcn_fdot2((a),(b),(c),false)
#else
#define FDOT2(a,b,c) ((c) + (float)(a).x*(float)(b).x + (float)(a).y*(float)(b).y)
#endif

// ---------------------------------------------------------------------------
// k_prep: repack W_hh into thread-local f16 layout for k_scan.
// Thread j (q=j&1, p=j>>1) owns outputs {2p,2p+1} with k in [128q,128q+128).
// Wp[j*256 + c*128 + i] = f16( W_hh[(128q+i)*768 + 2p+c] ), c in {0,1}.
// ---------------------------------------------------------------------------
template<typename T>
__device__ __forceinline__ void prep_body(const T* W_hh, _Float16* Wp){
  int j = blockIdx.x;          // 768 blocks
  int e = threadIdx.x;         // 256 threads -> e
  int q = j & 1, p = j >> 1;
  int c = e >> 7, i = e & 127;
  float v = ld1(W_hh, (size_t)(128*q + i) * G3 + 2*p + c);
  Wp[(size_t)j * 256 + e] = (_Float16)v;
}

__global__ __launch_bounds__(256) void k_prep(
    const void* __restrict__ W_hh, const void* __restrict__ W_ih,
    _Float16* __restrict__ Wp)
{
  if (detect_f32(W_ih)) prep_body<float>((const float*)W_hh, Wp);
  else                  prep_body<unsigned short>((const unsigned short*)W_hh, Wp);
}

// ---------------------------------------------------------------------------
// k_proj: proj[v][j] = b_ih[j] + sum_k embed[v][k]*W_ih[k][j]. Block = one v,
// 768 threads, coalesced W_ih reads. Block 0 also converts b_hh -> f32 bb[].
// ---------------------------------------------------------------------------
template<typename T>
__device__ __forceinline__ void proj_body(const T* embed, const T* W_ih,
                                          const T* b_ih, const T* b_hh,
                                          float* proj, float* bb){
  __shared__ float s_e[HH];
  int v = blockIdx.x, j = threadIdx.x;
  if (j < HH) s_e[j] = ld1(embed, (size_t)v * HH + j);
  if (v == 0) bb[j] = ld1(b_hh, (size_t)j);
  __syncthreads();
  float acc = ld1(b_ih, (size_t)j);
  #pragma unroll 8
  for (int k = 0; k < HH; k++)
    acc += s_e[k] * ld1(W_ih, (size_t)k * G3 + j);
  proj[(size_t)v * G3 + j] = acc;
}

__global__ __launch_bounds__(768) void k_proj(
    const void* __restrict__ embed, const void* __restrict__ W_ih,
    const void* __restrict__ b_ih, const void* __restrict__ b_hh,
    float* __restrict__ proj, float* __restrict__ bb)
{
  if (detect_f32(W_ih))
    proj_body<float>((const float*)embed, (const float*)W_ih,
                     (const float*)b_ih, (const float*)b_hh, proj, bb);
  else
    proj_body<unsigned short>((const unsigned short*)embed,
                              (const unsigned short*)W_ih,
                              (const unsigned short*)b_ih,
                              (const unsigned short*)b_hh, proj, bb);
}

// ---------------------------------------------------------------------------
// k_scan: GRU scan. One block per batch element, 768 threads.
// Pair-split dot: thread pair (2p,2p+1) -> outputs {2p,2p+1}; even lane does
// k in [0,128), odd lane k in [128,256); combine with shfl_xor(1).
// Per thread: 128 fdot2 + 16 broadcast ds_read_b128 (256B of s_h).
// ---------------------------------------------------------------------------
__global__ __launch_bounds__(768, 1) void k_scan(
    const int*      __restrict__ tokens,
    const _Float16* __restrict__ Wp,     // prepped weights
    const float*    __restrict__ bb,     // b_hh as f32
    const void*     __restrict__ W_ih,   // dtype detection (betas store)
    const float*    __restrict__ proj,
    unsigned short* __restrict__ outs,   // [B,T,H] bf16 scratch
    void*           __restrict__ d_out_base)
{
  __shared__ float s_proj[NVOC * G3];            // 55296 B
  __shared__ __align__(16) h2 s_h[HH / 2];       // 512 B f16 hidden state
  __shared__ float s_z[HH];
  __shared__ float s_n[HH];

  const bool f32m = detect_f32(W_ih);
  const int b = blockIdx.x;
  const int j = threadIdx.x;
  const int q16 = (j & 1) * 16;                  // k-half selector

  for (int i = j; i < NVOC * G3; i += 768) s_proj[i] = proj[i];

  // Weight cache: 128 VGPRs, branch-free init -> SROA promotes to registers.
  h2 wA[64], wB[64];
  {
    const float4* wp4 = (const float4*)(Wp + (size_t)j * 256);
    #pragma unroll
    for (int i = 0; i < 16; i++){
      float4 v = wp4[i];
      wA[4*i+0] = __builtin_bit_cast(h2, v.x);
      wA[4*i+1] = __builtin_bit_cast(h2, v.y);
      wA[4*i+2] = __builtin_bit_cast(h2, v.z);
      wA[4*i+3] = __builtin_bit_cast(h2, v.w);
    }
    #pragma unroll
    for (int i = 0; i < 16; i++){
      float4 v = wp4[16 + i];
      wB[4*i+0] = __builtin_bit_cast(h2, v.x);
      wB[4*i+1] = __builtin_bit_cast(h2, v.y);
      wB[4*i+2] = __builtin_bit_cast(h2, v.z);
      wB[4*i+3] = __builtin_bit_cast(h2, v.w);
    }
  }
  const float bhh = bb[j];

  if (j < HH/2) { h2 z; z.x = (_Float16)0.f; z.y = (_Float16)0.f; s_h[j] = z; }
  float h_old = 0.f;   // thread j<256 owns h[j]

  const int* tptr = tokens + (size_t)b * TT;
  int tok = tptr[0];
  unsigned short* orow   = outs + (size_t)b * TT * HH + j;
  // betas written by z-threads (j in [256,512)): beta index = j - 256
  unsigned short* brow_b = (unsigned short*)d_out_base + LOGITS_ELEMS
                           + (size_t)b * TT * HH + (j - HH);
  float*          brow_f = (float*)d_out_base + LOGITS_ELEMS
                           + (size_t)b * TT * HH + (j - HH);

  __syncthreads();

  for (int t = 0; t < TT; t++) {
    int tok_next = (t + 1 < TT) ? tptr[t + 1] : 0;
    const float* pj = s_proj + tok * G3;
    float gi  = pj[j];
    float gin = (j < HH) ? pj[2*HH + j] : 0.f;   // i_n for the tail threads

    // half-dot for outputs {2p, 2p+1}: 16 broadcast b128 reads, 128 fdot2
    float a0 = 0.f, a1 = 0.f, a2 = 0.f, a3 = 0.f;
    const int4* hp = (const int4*)s_h;
    #pragma unroll
    for (int i = 0; i < 16; i++) {
      int4 hv = hp[q16 + i];
      h2 x0 = __builtin_bit_cast(h2, hv.x);
      h2 x1 = __builtin_bit_cast(h2, hv.y);
      h2 x2 = __builtin_bit_cast(h2, hv.z);
      h2 x3 = __builtin_bit_cast(h2, hv.w);
      a0 = FDOT2(wA[4*i+0], x0, a0);
      a1 = FDOT2(wA[4*i+1], x1, a1);
      a0 = FDOT2(wA[4*i+2], x2, a0);
      a1 = FDOT2(wA[4*i+3], x3, a1);
      a2 = FDOT2(wB[4*i+0], x0, a2);
      a3 = FDOT2(wB[4*i+1], x1, a3);
      a2 = FDOT2(wB[4*i+2], x2, a2);
      a3 = FDOT2(wB[4*i+3], x3, a3);
    }
    float accA = a0 + a1;                        // partial for output 2p
    float accB = a2 + a3;                        // partial for output 2p+1
    accA += __shfl_xor(accA, 1);                 // combine k-halves
    accB += __shfl_xor(accB, 1);
    float gh = ((j & 1) ? accB : accA) + bhh;    // thread j <-> output j

    // wave-uniform gate split: j<256 -> r, 256..511 -> z, 512..767 -> n
    float r = 0.f;
    if (j >= 2*HH) {
      s_n[j - 2*HH] = gh;
    } else if (j >= HH) {
      float z = 1.f / (1.f + __expf(-(gi + gh)));
      s_z[j - HH] = z;
      if (f32m) brow_f[(size_t)t * HH] = z;      // beta store off critical tail
      else      brow_b[(size_t)t * HH] = f2bf(z);
    } else {
      r = 1.f / (1.f + __expf(-(gi + gh)));
    }
    __syncthreads();

    if (j < HH) {
      float z = s_z[j];
      float x = gin + r * s_n[j];                // i_n + r*h_n
      x = fminf(fmaxf(x, -15.f), 15.f);
      float e = __expf(2.f * x);
      float n = (e - 1.f) / (e + 1.f);           // tanh
      float hn = (1.f - z) * n + z * h_old;
      h_old = hn;
      ((_Float16*)s_h)[j] = (_Float16)hn;        // publish h for next step
      orow[(size_t)t * HH] = f2bf(hn);
    }
    __syncthreads();
    tok = tok_next;
  }
}

// ---------------------------------------------------------------------------
// k_head: logits = outs @ W_head + b_head
// ---------------------------------------------------------------------------
template<typename T>
__device__ __forceinline__ void stage_head(const T* W_head, const T* b_head,
                                           float* s_w, float* s_b, int tid){
  for (int i = tid; i < NOUT * HH; i += 256) {
    int o = i / HH, k = i - o * HH;
    s_w[i] = ld1(W_head, (size_t)k * NOUT + o);
  }
  if (tid < NOUT) s_b[tid] = ld1(b_head, (size_t)tid);
}

__global__ __launch_bounds__(256) void k_head(
    const unsigned short* __restrict__ outs,
    const void* __restrict__ W_head,
    const void* __restrict__ b_head,
    const void* __restrict__ W_ih,
    void* __restrict__ logits_out)
{
  __shared__ float s_w[NOUT * HH];
  __shared__ float s_b[NOUT];
  const bool f32m = detect_f32(W_ih);
  const int tid = threadIdx.x;

  if (f32m) stage_head<float>((const float*)W_head, (const float*)b_head,
                              s_w, s_b, tid);
  else      stage_head<unsigned short>((const unsigned short*)W_head,
                                       (const unsigned short*)b_head,
                                       s_w, s_b, tid);
  __syncthreads();

  size_t gid = (size_t)blockIdx.x * 256 + tid;
  if (gid >= LOGITS_ELEMS) return;
  int o = (int)(gid % NOUT);
  size_t row = gid / NOUT;

  const uint4* xp = (const uint4*)(outs + row * HH);
  const float* wv = s_w + o * HH;
  float a0 = 0.f, a1 = 0.f, a2 = 0.f, a3 = 0.f;
  #pragma unroll 8
  for (int kk = 0; kk < 32; kk++) {
    uint4 u = xp[kk];
    int kb = kk * 8;
    a0 += bflo(u.x) * wv[kb+0] + bfhi(u.x) * wv[kb+1];
    a1 += bflo(u.y) * wv[kb+2] + bfhi(u.y) * wv[kb+3];
    a2 += bflo(u.z) * wv[kb+4] + bfhi(u.z) * wv[kb+5];
    a3 += bflo(u.w) * wv[kb+6] + bfhi(u.w) * wv[kb+7];
  }
  float val = ((a0 + a1) + (a2 + a3)) + s_b[o];
  if (f32m) ((float*)logits_out)[gid] = val;
  else      ((unsigned short*)logits_out)[gid] = f2bf(val);
}

// ---------------------------------------------------------------------------
extern "C" void kernel_launch(void* const* d_in, const int* in_sizes, int n_in,
                              void* d_out, int out_size, void* d_ws, size_t ws_size,
                              hipStream_t stream)
{
  // inputs: tokens, embed, W_ih, W_hh, b_ih, b_hh, W_head, b_head
  const int* tokens = (const int*)d_in[0];
  const void* embed  = d_in[1];
  const void* W_ih   = d_in[2];
  const void* W_hh   = d_in[3];
  const void* b_ih   = d_in[4];
  const void* b_hh   = d_in[5];
  const void* W_head = d_in[6];
  const void* b_head = d_in[7];

  // workspace layout (16B aligned):
  // proj: 13824 f32 = 55296 B | bb: 768 f32 = 3072 B | Wp: 196608 f16 = 393216 B | outs
  char* ws = (char*)d_ws;
  float*          proj = (float*)ws;
  float*          bb   = (float*)(ws + 55296);
  _Float16*       Wp   = (_Float16*)(ws + 55296 + 3072);
  unsigned short* outs = (unsigned short*)(ws + 55296 + 3072 + 393216);

  k_prep<<<G3, 256, 0, stream>>>(W_hh, W_ih, Wp);
  k_proj<<<NVOC, G3, 0, stream>>>(embed, W_ih, b_ih, b_hh, proj, bb);
  k_scan<<<BB, G3, 0, stream>>>(tokens, Wp, bb, W_ih, proj, outs, d_out);
  k_head<<<(int)((LOGITS_ELEMS + 255) / 256), 256, 0, stream>>>(
      outs, W_head, b_head, W_ih, d_out);
}